// Round 4
// baseline (158.363 us; speedup 1.0000x reference)
//
#include <hip/hip_runtime.h>

// Problem: B=2048, N=512, C=64, L=2, O=8192
//   connections = argmax_c weights[c,l,o]          -> [L,O]
//   sel[l,o]    = indices[connections[l,o], l, o]  -> [L,O]
//   out[b,l,o]  = x[b, sel[l,o]]                   -> [B,L,O] fp32 (128 MiB)
//
// Floor: ~132 MiB HBM traffic (128 MiB out writes + 4 MiB x) @ ~6.7 TB/s
// achievable ≈ 20 us. R2 structure: 8 batch rows/block, sel int4 reused
// for 8 float4 stores. R3b change: nontemporal output stores via a native
// clang vector type (HIP float4 is a class — builtin rejects it).

#define BB 2048
#define NN 512
#define CC 64
#define LL 2
#define OO 8192
#define LO (LL * OO)       // 16384
#define ROWS 8             // batch rows per block
#define CHUNK 4096         // lo elements per block
#define NCHUNK (LO / CHUNK)            // 4
#define ITERS (CHUNK / (256 * 4))      // 4 iterations of int4/float4 per thread

typedef float vfloat4 __attribute__((ext_vector_type(4)));  // native vector for nt store

__global__ void sel_kernel(const float* __restrict__ weights,
                           const int* __restrict__ indices,
                           int* __restrict__ sel) {
    int t = blockIdx.x * blockDim.x + threadIdx.x;  // t = l*O + o
    if (t >= LO) return;
    float best = weights[t];
    int bestc = 0;
#pragma unroll 8
    for (int c = 1; c < CC; ++c) {
        float w = weights[(size_t)c * LO + t];
        if (w > best) { best = w; bestc = c; }  // strict > keeps first-max (JAX argmax)
    }
    sel[t] = indices[(size_t)bestc * LO + t];
}

__global__ void __launch_bounds__(256)
gather_kernel(const float* __restrict__ x,
              const int* __restrict__ sel,
              float* __restrict__ out) {
    __shared__ float xrows[ROWS * NN];   // 16 KiB: 8 contiguous batch rows of x

    const int rg    = blockIdx.x / NCHUNK;       // row group [0, 256)
    const int chunk = blockIdx.x % NCHUNK;       // lo chunk  [0, 4)
    const int b0    = rg * ROWS;

    // Stage 8 contiguous x rows (4096 floats) with coalesced float4 loads.
    const float4* xp4 = reinterpret_cast<const float4*>(x + (size_t)b0 * NN);
    float4* sh4 = reinterpret_cast<float4*>(xrows);
#pragma unroll
    for (int i = 0; i < (ROWS * NN / 4) / 256; ++i)   // 4 iterations
        sh4[i * 256 + threadIdx.x] = xp4[i * 256 + threadIdx.x];
    __syncthreads();

    const int* selp = sel + chunk * CHUNK;
    float* op = out + (size_t)b0 * LO + chunk * CHUNK;

#pragma unroll
    for (int i = 0; i < ITERS; ++i) {
        const int base = i * 1024 + threadIdx.x * 4;
        int4 s = *reinterpret_cast<const int4*>(selp + base);
#pragma unroll
        for (int r = 0; r < ROWS; ++r) {
            const float* row = xrows + r * NN;
            vfloat4 v;
            v.x = row[s.x];
            v.y = row[s.y];
            v.z = row[s.z];
            v.w = row[s.w];
            // write-once stream: bypass L2 (global_store_dwordx4 nt)
            __builtin_nontemporal_store(
                v, reinterpret_cast<vfloat4*>(op + (size_t)r * LO + base));
        }
    }
}

extern "C" void kernel_launch(void* const* d_in, const int* in_sizes, int n_in,
                              void* d_out, int out_size, void* d_ws, size_t ws_size,
                              hipStream_t stream) {
    const float* x       = (const float*)d_in[0];   // [B, N]
    const float* weights = (const float*)d_in[1];   // [C, L, O]
    const int*   indices = (const int*)d_in[2];     // [C, L, O]
    float*       out     = (float*)d_out;           // [B, L, O]
    int*         sel     = (int*)d_ws;              // [L*O] scratch (64 KiB)

    sel_kernel<<<LO / 256, 256, 0, stream>>>(weights, indices, sel);
    gather_kernel<<<(BB / ROWS) * NCHUNK, 256, 0, stream>>>(x, sel, out);
}

// Round 5
// 150.910 us; speedup vs baseline: 1.0494x; 1.0494x over previous
//
#include <hip/hip_runtime.h>

// Problem: B=2048, N=512, C=64, L=2, O=8192
//   connections = argmax_c weights[c,l,o]          -> [L,O]
//   sel[l,o]    = indices[connections[l,o], l, o]  -> [L,O]
//   out[b,l,o]  = x[b, sel[l,o]]                   -> [B,L,O] fp32 (128 MiB)
//
// Final structure (R2, best measured 150.8 us):
//   - sel_kernel: 16K threads, strict-> argmax over C=64 (JAX first-max ties).
//   - gather_kernel: 8 batch rows x 4096-wide chunk per block; sel int4 loaded
//     once feeds 8 coalesced float4 stores; 8 x-rows staged in 16 KiB LDS.
// R4 post-mortem: nontemporal stores REGRESSED (+7.6 us) — for a fully
// coalesced write stream, L2 write-combining beats nt bypass. Reverted.
// Controllable floor: ~132 MiB HBM traffic @ ~6.4 TB/s ≈ 21 us gather
// + ~5 us sel + launch overhead; remainder of dur_us is harness traffic.

#define BB 2048
#define NN 512
#define CC 64
#define LL 2
#define OO 8192
#define LO (LL * OO)       // 16384
#define ROWS 8             // batch rows per block
#define CHUNK 4096         // lo elements per block
#define NCHUNK (LO / CHUNK)            // 4
#define ITERS (CHUNK / (256 * 4))      // 4 iterations of int4/float4 per thread

__global__ void sel_kernel(const float* __restrict__ weights,
                           const int* __restrict__ indices,
                           int* __restrict__ sel) {
    int t = blockIdx.x * blockDim.x + threadIdx.x;  // t = l*O + o
    if (t >= LO) return;
    float best = weights[t];
    int bestc = 0;
#pragma unroll 8
    for (int c = 1; c < CC; ++c) {
        float w = weights[(size_t)c * LO + t];
        if (w > best) { best = w; bestc = c; }  // strict > keeps first-max (JAX argmax)
    }
    sel[t] = indices[(size_t)bestc * LO + t];
}

__global__ void __launch_bounds__(256)
gather_kernel(const float* __restrict__ x,
              const int* __restrict__ sel,
              float* __restrict__ out) {
    __shared__ float xrows[ROWS * NN];   // 16 KiB: 8 contiguous batch rows of x

    const int rg    = blockIdx.x / NCHUNK;       // row group [0, 256)
    const int chunk = blockIdx.x % NCHUNK;       // lo chunk  [0, 4)
    const int b0    = rg * ROWS;

    // Stage 8 contiguous x rows (4096 floats) with coalesced float4 loads.
    const float4* xp4 = reinterpret_cast<const float4*>(x + (size_t)b0 * NN);
    float4* sh4 = reinterpret_cast<float4*>(xrows);
#pragma unroll
    for (int i = 0; i < (ROWS * NN / 4) / 256; ++i)   // 4 iterations
        sh4[i * 256 + threadIdx.x] = xp4[i * 256 + threadIdx.x];
    __syncthreads();

    const int* selp = sel + chunk * CHUNK;
    float* op = out + (size_t)b0 * LO + chunk * CHUNK;

#pragma unroll
    for (int i = 0; i < ITERS; ++i) {
        const int base = i * 1024 + threadIdx.x * 4;
        int4 s = *reinterpret_cast<const int4*>(selp + base);
#pragma unroll
        for (int r = 0; r < ROWS; ++r) {
            const float* row = xrows + r * NN;
            float4 v;
            v.x = row[s.x];
            v.y = row[s.y];
            v.z = row[s.z];
            v.w = row[s.w];
            *reinterpret_cast<float4*>(op + (size_t)r * LO + base) = v;
        }
    }
}

extern "C" void kernel_launch(void* const* d_in, const int* in_sizes, int n_in,
                              void* d_out, int out_size, void* d_ws, size_t ws_size,
                              hipStream_t stream) {
    const float* x       = (const float*)d_in[0];   // [B, N]
    const float* weights = (const float*)d_in[1];   // [C, L, O]
    const int*   indices = (const int*)d_in[2];     // [C, L, O]
    float*       out     = (float*)d_out;           // [B, L, O]
    int*         sel     = (int*)d_ws;              // [L*O] scratch (64 KiB)

    sel_kernel<<<LO / 256, 256, 0, stream>>>(weights, indices, sel);
    gather_kernel<<<(BB / ROWS) * NCHUNK, 256, 0, stream>>>(x, sel, out);
}